// Round 14
// baseline (102.218 us; speedup 1.0000x reference)
//
#include <hip/hip_runtime.h>
#include <stdint.h>

#define NH 16
#define DKH 64
#define SEQ 2048
#define NBATCH 2
#define NROW (NBATCH*SEQ)   // 4096
#define DM 1024
#define LOG2E 1.44269504088896f

typedef __attribute__((ext_vector_type(8))) __bf16 bf16x8;
typedef __attribute__((ext_vector_type(4))) __bf16 bf16x4;
typedef __attribute__((ext_vector_type(4))) float f32x4;

#if __has_builtin(__builtin_amdgcn_exp2f)
#define EXP2(x) __builtin_amdgcn_exp2f(x)
#else
#define EXP2(x) exp2f(x)
#endif

__device__ __forceinline__ unsigned short f2bf(float f) {
  union { float f; uint32_t u; } v; v.f = f;
  uint32_t r = v.u + 0x7FFFu + ((v.u >> 16) & 1u);
  return (unsigned short)(r >> 16);
}
__device__ __forceinline__ f32x4 mfma16(bf16x8 a, bf16x8 b, f32x4 c) {
  return __builtin_amdgcn_mfma_f32_16x16x32_bf16(a, b, c, 0, 0, 0);
}
// async global->LDS, 16B/lane; LDS dest = wave-uniform base + lane*16
__device__ __forceinline__ void gload_lds16(const void* g, void* l) {
  __builtin_amdgcn_global_load_lds(
      (__attribute__((address_space(1))) uint32_t*)(uintptr_t)g,
      (__attribute__((address_space(3))) uint32_t*)(uintptr_t)l,
      16, 0, 0);
}
__device__ __forceinline__ void barrier_raw() {
  asm volatile("" ::: "memory");
  __builtin_amdgcn_s_barrier();
  asm volatile("" ::: "memory");
}

// ---------------- k0: x f32 -> bf16 ----------------
__global__ __launch_bounds__(256) void k_cvt_x(const float* __restrict__ x,
                                               unsigned short* __restrict__ xb) {
  int i = blockIdx.x * 256 + threadIdx.x;
  float4 v = ((const float4*)x)[i];
  ushort4 o;
  o.x = f2bf(v.x); o.y = f2bf(v.y); o.z = f2bf(v.z); o.w = f2bf(v.w);
  ((ushort4*)xb)[i] = o;
}

// ---------------- k1: W[k][n] f32 -> Wt[n][k] bf16 ------------------------
__global__ __launch_bounds__(256) void k_cvt_w(
    const float* __restrict__ Wq, const float* __restrict__ Wk,
    const float* __restrict__ Wv, const float* __restrict__ Wo,
    unsigned short* __restrict__ Wqt, unsigned short* __restrict__ Wkt,
    unsigned short* __restrict__ Wvt, unsigned short* __restrict__ Wot) {
  __shared__ float tile[32][33];
  int z = blockIdx.z;
  const float* W = (z == 0) ? Wq : (z == 1) ? Wk : (z == 2) ? Wv : Wo;
  int ti = blockIdx.x, tj = blockIdx.y;      // k-tile, n-tile
  int c = threadIdx.x & 31, r0 = threadIdx.x >> 5;
#pragma unroll
  for (int rr = 0; rr < 4; ++rr) {
    int r = r0 + rr * 8;
    tile[r][c] = W[(ti * 32 + r) * DM + tj * 32 + c];
  }
  __syncthreads();
  unsigned short* Out = (z == 0) ? Wqt : (z == 1) ? Wkt : (z == 2) ? Wvt : Wot;
#pragma unroll
  for (int rr = 0; rr < 4; ++rr) {
    int a = r0 + rr * 8;                     // n within tile
    float v = tile[c][a];                    // = W[ti*32+c][tj*32+a]
    Out[(tj * 32 + a) * DM + ti * 32 + c] = f2bf(v);
  }
}

// ---------------- k2: QKV projection GEMM (dbuf, counted vmcnt) -----------
__global__ __launch_bounds__(256) void k_gemm_qkv(
    const unsigned short* __restrict__ xb,
    const unsigned short* __restrict__ Wqt, const unsigned short* __restrict__ Wkt,
    const unsigned short* __restrict__ Wvt,
    const float* __restrict__ bq, const float* __restrict__ bk,
    const float* __restrict__ bv,
    unsigned short* __restrict__ Q, unsigned short* __restrict__ Ko,
    unsigned short* __restrict__ Vt) {
  __shared__ __align__(16) unsigned short Al[2][128 * 64];
  __shared__ __align__(16) unsigned short Bl[2][128 * 64];
  int z = blockIdx.z;
  const unsigned short* Wt = (z == 0) ? Wqt : (z == 1) ? Wkt : Wvt;
  const float* bias = (z == 0) ? bq : (z == 1) ? bk : bv;

  int m0 = blockIdx.x * 128, n0 = blockIdx.y * 128;
  int tid = threadIdx.x, lane = tid & 63, wave = tid >> 6;
  int wr = wave >> 1, wc = wave & 1;
  int l15 = lane & 15, lg = lane >> 4;
  int r3 = lane >> 3, s3 = lane & 7;
  int gsw = (s3 ^ r3) << 4;      // pre-swizzled source slot (bytes), row&7 == r3
  int swz = l15 & 7;             // read-side row XOR

  f32x4 acc[4][4] = {};

  auto stage = [&](int kb, int b) {
#pragma unroll
    for (int c = 0; c < 4; ++c) {
      int rb = c * 32 + wave * 8;            // wave-uniform row base (mult of 8)
      gload_lds16((const char*)xb + (size_t)(m0 + rb + r3) * 2048 + kb * 128 + gsw,
                  (char*)&Al[b][0] + rb * 128);
      gload_lds16((const char*)Wt + (size_t)(n0 + rb + r3) * 2048 + kb * 128 + gsw,
                  (char*)&Bl[b][0] + rb * 128);
    }
  };

  stage(0, 0);
  stage(1, 1);

  for (int kb = 0; kb < 16; ++kb) {
    if (kb < 15) asm volatile("s_waitcnt vmcnt(8)" ::: "memory");
    else         asm volatile("s_waitcnt vmcnt(0)" ::: "memory");
    barrier_raw();
    int b = kb & 1;
#pragma unroll
    for (int ks = 0; ks < 2; ++ks) {
      int slot = lg + 4 * ks;
      int sofs = ((slot ^ swz) << 4);
      bf16x8 a[4], bfr[4];
#pragma unroll
      for (int mt = 0; mt < 4; ++mt)
        a[mt] = *(const bf16x8*)((const char*)&Al[b][0] + (wr * 64 + mt * 16 + l15) * 128 + sofs);
#pragma unroll
      for (int nt = 0; nt < 4; ++nt)
        bfr[nt] = *(const bf16x8*)((const char*)&Bl[b][0] + (wc * 64 + nt * 16 + l15) * 128 + sofs);
#pragma unroll
      for (int mt = 0; mt < 4; ++mt)
#pragma unroll
        for (int nt = 0; nt < 4; ++nt)
          acc[mt][nt] = mfma16(a[mt], bfr[nt], acc[mt][nt]);
    }
    barrier_raw();
    if (kb < 14) stage(kb + 2, b);
  }

#pragma unroll
  for (int nt = 0; nt < 4; ++nt) {
    int n = n0 + wc * 64 + nt * 16 + l15;
    float bb = bias[n];
    int h = n >> 6, dk = n & 63;
#pragma unroll
    for (int mt = 0; mt < 4; ++mt) {
      int mbase = m0 + wr * 64 + mt * 16 + lg * 4;
      int bidx = mbase >> 11, s = mbase & 2047;
      if (z < 2) {
        unsigned short* Out = (z == 0) ? Q : Ko;
#pragma unroll
        for (int r = 0; r < 4; ++r)
          Out[(((size_t)(bidx * NH + h)) * SEQ + s + r) * DKH + dk] =
              f2bf(acc[mt][nt][r] + bb);
      } else {
        ushort4 pk;
        pk.x = f2bf(acc[mt][nt][0] + bb);
        pk.y = f2bf(acc[mt][nt][1] + bb);
        pk.z = f2bf(acc[mt][nt][2] + bb);
        pk.w = f2bf(acc[mt][nt][3] + bb);
        *(ushort4*)&Vt[((size_t)(bidx * NH + h) * DKH + dk) * SEQ + s] = pk;
      }
    }
  }
}

// ---------------- k3: chunk-causal flash attention (v9) -------------------
// v8 + CU-sum equalization: qc(g) = (g<16) ? 31-g : g-16 makes every CU quad
// {31-a, 23-a, a, a+8} -> 66 tiles per CU (was 52..80 under qc=31-g).
// bh = blk&31 (XCD L2 affinity) unchanged.
__global__ __launch_bounds__(256) void k_attn(
    const unsigned short* __restrict__ Qg, const unsigned short* __restrict__ Kg,
    const unsigned short* __restrict__ Vtg, const float* __restrict__ rel_bias,
    unsigned short* __restrict__ AOh) {
  __shared__ __align__(16) unsigned short Kl[2][64 * 64];
  __shared__ __align__(16) unsigned short Vl[2][64 * 64];
  __shared__ float biasl[257];

  int blk = blockIdx.x;
  int bh = blk & 31;
  int g = blk >> 5;
  int qc = (g < 16) ? (31 - g) : (g - 16);   // balanced per-CU quads
  int h = bh & 15, bidx = bh >> 4;
  int tid = threadIdx.x, lane = tid & 63, wave = tid >> 6;
  int l15 = lane & 15, lg = lane >> 4;
  int r3 = lane >> 3, s3 = lane & 7;
  int gsw = (s3 ^ r3) * 16;   // pre-swizzled source slot (bytes)

  const float C1L = 0.125f * LOG2E;

  // bias table pre-scaled: (rel_bias - 6) * log2(e)
  for (int i = tid; i < 257; i += 256)
    biasl[i] = rel_bias[i * NH + h] * LOG2E - 6.0f * LOG2E;

  // Q fragments in registers for the whole block (B-operand: lane l15 = q)
  int qrow = qc * 64 + wave * 16 + l15;
  const unsigned short* qptr = Qg + ((size_t)bh * SEQ + qrow) * DKH + lg * 8;
  bf16x8 qf0 = *(const bf16x8*)(qptr);
  bf16x8 qf1 = *(const bf16x8*)(qptr + 32);

  const char* kcb = (const char*)(Kg + (size_t)bh * SEQ * DKH);
  const char* vcb = (const char*)(Vtg + (size_t)bh * DKH * SEQ);

  // stage K/V chunk j into buffer b: LDS[row][slot16] = G[row][slot16 ^ (row&7)]
  auto stage = [&](int j, int b) {
    const char* kj = kcb + (size_t)j * (64 * DKH * 2);
    const char* vj = vcb + (size_t)j * 128;
#pragma unroll
    for (int c = 0; c < 2; ++c) {
      int rb = wave * 16 + c * 8;          // wave-uniform row base
      gload_lds16(kj + (size_t)(rb + r3) * 128 + gsw,
                  (char*)&Kl[b][0] + rb * 128);
      gload_lds16(vj + (size_t)(rb + r3) * (SEQ * 2) + gsw,
                  (char*)&Vl[b][0] + rb * 128);
    }
  };

  float lsum = 0.f;
  f32x4 acc[4] = {};
  float cfar = rel_bias[256 * NH + h] * LOG2E - 6.0f * LOG2E;
  int swz = (l15 & 7);

  // V-read byte offsets within a row for the 4 kt chunks (8B each)
  int vo[4];
#pragma unroll
  for (int kt = 0; kt < 4; ++kt)
    vo[kt] = (((kt * 2 + (lg >> 1)) ^ swz) << 4) + ((lg & 1) << 3);

  stage(0, 0);
  if (qc > 0) stage(1, 1);

  for (int j = 0; j <= qc; ++j) {
    int cur = j & 1;
    // counted wait: tile j's 4 loads done; tile j+1's 4 stay in flight
    if (j < qc) asm volatile("s_waitcnt vmcnt(4)" ::: "memory");
    else        asm volatile("s_waitcnt vmcnt(0)" ::: "memory");
    barrier_raw();

    const char* Kc = (const char*)&Kl[cur][0];
    const char* Vc = (const char*)&Vl[cur][0];

    // QK^T swapped: A = K rows (m = key), B = Q (n = q = l15)
    // sa[kt][r] -> k = j*64 + kt*16 + lg*4 + r ; q = qrow (lane-fixed)
    f32x4 sa[4] = {};
    __builtin_amdgcn_s_setprio(1);
#pragma unroll
    for (int ks = 0; ks < 2; ++ks) {
      bf16x8 qa = ks ? qf1 : qf0;
      int slot = lg + 4 * ks;
#pragma unroll
      for (int kt = 0; kt < 4; ++kt) {
        bf16x8 kfr = *(const bf16x8*)(Kc + (kt * 16 + l15) * 128 + ((slot ^ swz) * 16));
        sa[kt] = mfma16(kfr, qa, sa[kt]);
      }
    }
    __builtin_amdgcn_s_setprio(0);

    // p = exp2(s*C1L + bias); far tiles (j <= qc-3) have constant bias
    float p[4][4];
    if (j >= qc - 2) {
      int kb0 = j * 64 + lg * 4;
#pragma unroll
      for (int kt = 0; kt < 4; ++kt)
#pragma unroll
        for (int r = 0; r < 4; ++r) {
          int rel = qrow - (kb0 + kt * 16 + r);
          rel = min(max(rel, -128), 128) + 128;
          p[kt][r] = EXP2(fmaf(sa[kt][r], C1L, biasl[rel]));
        }
    } else {
#pragma unroll
      for (int kt = 0; kt < 4; ++kt)
#pragma unroll
        for (int r = 0; r < 4; ++r)
          p[kt][r] = EXP2(fmaf(sa[kt][r], C1L, cfar));
    }
#pragma unroll
    for (int kt = 0; kt < 4; ++kt)
      lsum += (p[kt][0] + p[kt][1]) + (p[kt][2] + p[kt][3]);

    // pack P in-register as PV A-fragments (lane l15 = q = A's m-row):
    // pfr_h slot jj holds key (2h + (jj>>2))*16 + lg*4 + (jj&3) — lane-local.
    bf16x8 pfr0, pfr1;
#pragma unroll
    for (int jj = 0; jj < 4; ++jj) {
      pfr0[jj]     = (__bf16)p[0][jj];
      pfr0[jj + 4] = (__bf16)p[1][jj];
      pfr1[jj]     = (__bf16)p[2][jj];
      pfr1[jj + 4] = (__bf16)p[3][jj];
    }

    // PV: B = V assembled with the SAME key bijection (2x b64 per dt,half)
    __builtin_amdgcn_s_setprio(1);
#pragma unroll
    for (int dt = 0; dt < 4; ++dt) {
      const char* vrow = Vc + (dt * 16 + l15) * 128;
      uint2 t0 = *(const uint2*)(vrow + vo[0]);
      uint2 t1 = *(const uint2*)(vrow + vo[1]);
      uint2 t2 = *(const uint2*)(vrow + vo[2]);
      uint2 t3 = *(const uint2*)(vrow + vo[3]);
      uint4 w0, w1;
      w0.x = t0.x; w0.y = t0.y; w0.z = t1.x; w0.w = t1.y;
      w1.x = t2.x; w1.y = t2.y; w1.z = t3.x; w1.w = t3.y;
      acc[dt] = mfma16(pfr0, *(const bf16x8*)&w0, acc[dt]);
      acc[dt] = mfma16(pfr1, *(const bf16x8*)&w1, acc[dt]);
    }
    __builtin_amdgcn_s_setprio(0);

    barrier_raw();                       // all waves done reading buf cur
    if (j + 2 <= qc) stage(j + 2, cur);  // refill consumed buffer
  }

  // deferred row-sum: lanes sharing l15 hold disjoint k-partials
  lsum += __shfl_xor(lsum, 16);
  lsum += __shfl_xor(lsum, 32);

  // epilogue: normalize, write bf16 [4096][1024]
#pragma unroll
  for (int r = 0; r < 4; ++r) {
    float inv = 1.0f / __shfl(lsum, lg * 4 + r, 64);
    int s = qc * 64 + wave * 16 + lg * 4 + r;
    size_t row = (size_t)bidx * SEQ + s;
#pragma unroll
    for (int dt = 0; dt < 4; ++dt) {
      float v = acc[dt][r] * inv;
      int col = h * 64 + dt * 16 + l15;
      AOh[row * DM + col] = f2bf(v);
    }
  }
}

// ---------------- k4: output GEMM, 64x128 tile (dbuf, vmcnt(6)) -----------
// Retiled from 128x128: grid (64,8)=512 blocks -> 2 resident blocks/CU
// (was 256 blocks = 1/CU, 4 waves). LDS 48KB. acc[2][4] per wave.
__global__ __launch_bounds__(256) void k_gemm_out(
    const unsigned short* __restrict__ Ab, const unsigned short* __restrict__ Bt,
    const float* __restrict__ bo, float* __restrict__ out) {
  __shared__ __align__(16) unsigned short Al[2][64 * 64];
  __shared__ __align__(16) unsigned short Bl[2][128 * 64];

  int m0 = blockIdx.x * 64, n0 = blockIdx.y * 128;
  int tid = threadIdx.x, lane = tid & 63, wave = tid >> 6;
  int wr = wave >> 1, wc = wave & 1;
  int l15 = lane & 15, lg = lane >> 4;
  int r3 = lane >> 3, s3 = lane & 7;
  int gsw = (s3 ^ r3) << 4;
  int swz = l15 & 7;

  f32x4 acc[2][4] = {};

  auto stage = [&](int kb, int b) {
#pragma unroll
    for (int c = 0; c < 2; ++c) {       // A: 64 rows
      int rb = c * 32 + wave * 8;
      gload_lds16((const char*)Ab + (size_t)(m0 + rb + r3) * 2048 + kb * 128 + gsw,
                  (char*)&Al[b][0] + rb * 128);
    }
#pragma unroll
    for (int c = 0; c < 4; ++c) {       // B: 128 rows
      int rb = c * 32 + wave * 8;
      gload_lds16((const char*)Bt + (size_t)(n0 + rb + r3) * 2048 + kb * 128 + gsw,
                  (char*)&Bl[b][0] + rb * 128);
    }
  };

  stage(0, 0);
  stage(1, 1);

  for (int kb = 0; kb < 16; ++kb) {
    if (kb < 15) asm volatile("s_waitcnt vmcnt(6)" ::: "memory");
    else         asm volatile("s_waitcnt vmcnt(0)" ::: "memory");
    barrier_raw();
    int b = kb & 1;
#pragma unroll
    for (int ks = 0; ks < 2; ++ks) {
      int slot = lg + 4 * ks;
      int sofs = ((slot ^ swz) << 4);
      bf16x8 a[2], bfr[4];
#pragma unroll
      for (int mt = 0; mt < 2; ++mt)
        a[mt] = *(const bf16x8*)((const char*)&Al[b][0] + (wr * 32 + mt * 16 + l15) * 128 + sofs);
#pragma unroll
      for (int nt = 0; nt < 4; ++nt)
        bfr[nt] = *(const bf16x8*)((const char*)&Bl[b][0] + (wc * 64 + nt * 16 + l15) * 128 + sofs);
#pragma unroll
      for (int mt = 0; mt < 2; ++mt)
#pragma unroll
        for (int nt = 0; nt < 4; ++nt)
          acc[mt][nt] = mfma16(a[mt], bfr[nt], acc[mt][nt]);
    }
    barrier_raw();
    if (kb < 14) stage(kb + 2, b);
  }

#pragma unroll
  for (int nt = 0; nt < 4; ++nt) {
    int n = n0 + wc * 64 + nt * 16 + l15;
    float bb = bo[n];
#pragma unroll
    for (int mt = 0; mt < 2; ++mt) {
      int mbase = m0 + wr * 32 + mt * 16 + lg * 4;
#pragma unroll
      for (int r = 0; r < 4; ++r)
        out[(size_t)(mbase + r) * DM + n] = acc[mt][nt][r] + bb;
    }
  }
}

// ---------------- launch ---------------------------------------------------
extern "C" void kernel_launch(void* const* d_in, const int* in_sizes, int n_in,
                              void* d_out, int out_size, void* d_ws, size_t ws_size,
                              hipStream_t stream) {
  const float* x  = (const float*)d_in[0];
  const float* Wq = (const float*)d_in[1];
  const float* bq = (const float*)d_in[2];
  const float* Wk = (const float*)d_in[3];
  const float* bk = (const float*)d_in[4];
  const float* Wv = (const float*)d_in[5];
  const float* bv = (const float*)d_in[6];
  const float* Wo = (const float*)d_in[7];
  const float* bo = (const float*)d_in[8];
  const float* rb = (const float*)d_in[9];
  float* out = (float*)d_out;

  char* ws = (char*)d_ws;
  size_t off = 0;
  auto alloc = [&](size_t bytes) {
    char* p = ws + off; off += (bytes + 255) & ~(size_t)255; return p;
  };
  unsigned short* xb   = (unsigned short*)alloc((size_t)NROW * DM * 2);
  unsigned short* Wqt  = (unsigned short*)alloc((size_t)DM * DM * 2);
  unsigned short* Wkt  = (unsigned short*)alloc((size_t)DM * DM * 2);
  unsigned short* Wvt  = (unsigned short*)alloc((size_t)DM * DM * 2);
  unsigned short* Wot  = (unsigned short*)alloc((size_t)DM * DM * 2);
  unsigned short* Qb   = (unsigned short*)alloc((size_t)NROW * DM * 2);
  unsigned short* Kb   = (unsigned short*)alloc((size_t)NROW * DM * 2);
  unsigned short* Vtb  = (unsigned short*)alloc((size_t)NROW * DM * 2);
  unsigned short* AOh  = (unsigned short*)alloc((size_t)NROW * DM * 2);

  k_cvt_x<<<dim3(NROW * DM / 4 / 256), dim3(256), 0, stream>>>(x, xb);
  k_cvt_w<<<dim3(32, 32, 4), dim3(256), 0, stream>>>(Wq, Wk, Wv, Wo,
                                                     Wqt, Wkt, Wvt, Wot);
  k_gemm_qkv<<<dim3(32, 8, 3), dim3(256), 0, stream>>>(xb, Wqt, Wkt, Wvt,
                                                       bq, bk, bv, Qb, Kb, Vtb);
  k_attn<<<dim3(1024), dim3(256), 0, stream>>>(Qb, Kb, Vtb, rb, AOh);
  k_gemm_out<<<dim3(64, 8), dim3(256), 0, stream>>>(AOh, Wot, bo, out);
}

// Round 15
// 100.133 us; speedup vs baseline: 1.0208x; 1.0208x over previous
//
#include <hip/hip_runtime.h>
#include <stdint.h>

#define NH 16
#define DKH 64
#define SEQ 2048
#define NBATCH 2
#define NROW (NBATCH*SEQ)   // 4096
#define DM 1024
#define LOG2E 1.44269504088896f

typedef __attribute__((ext_vector_type(8))) __bf16 bf16x8;
typedef __attribute__((ext_vector_type(4))) __bf16 bf16x4;
typedef __attribute__((ext_vector_type(4))) float f32x4;

#if __has_builtin(__builtin_amdgcn_exp2f)
#define EXP2(x) __builtin_amdgcn_exp2f(x)
#else
#define EXP2(x) exp2f(x)
#endif

__device__ __forceinline__ unsigned short f2bf(float f) {
  union { float f; uint32_t u; } v; v.f = f;
  uint32_t r = v.u + 0x7FFFu + ((v.u >> 16) & 1u);
  return (unsigned short)(r >> 16);
}
__device__ __forceinline__ f32x4 mfma16(bf16x8 a, bf16x8 b, f32x4 c) {
  return __builtin_amdgcn_mfma_f32_16x16x32_bf16(a, b, c, 0, 0, 0);
}
// async global->LDS, 16B/lane; LDS dest = wave-uniform base + lane*16
__device__ __forceinline__ void gload_lds16(const void* g, void* l) {
  __builtin_amdgcn_global_load_lds(
      (__attribute__((address_space(1))) uint32_t*)(uintptr_t)g,
      (__attribute__((address_space(3))) uint32_t*)(uintptr_t)l,
      16, 0, 0);
}
__device__ __forceinline__ void barrier_raw() {
  asm volatile("" ::: "memory");
  __builtin_amdgcn_s_barrier();
  asm volatile("" ::: "memory");
}

// ---------------- k0: x f32 -> bf16 ----------------
__global__ __launch_bounds__(256) void k_cvt_x(const float* __restrict__ x,
                                               unsigned short* __restrict__ xb) {
  int i = blockIdx.x * 256 + threadIdx.x;
  float4 v = ((const float4*)x)[i];
  ushort4 o;
  o.x = f2bf(v.x); o.y = f2bf(v.y); o.z = f2bf(v.z); o.w = f2bf(v.w);
  ((ushort4*)xb)[i] = o;
}

// ---------------- k1: W[k][n] f32 -> Wt[n][k] bf16 ------------------------
__global__ __launch_bounds__(256) void k_cvt_w(
    const float* __restrict__ Wq, const float* __restrict__ Wk,
    const float* __restrict__ Wv, const float* __restrict__ Wo,
    unsigned short* __restrict__ Wqt, unsigned short* __restrict__ Wkt,
    unsigned short* __restrict__ Wvt, unsigned short* __restrict__ Wot) {
  __shared__ float tile[32][33];
  int z = blockIdx.z;
  const float* W = (z == 0) ? Wq : (z == 1) ? Wk : (z == 2) ? Wv : Wo;
  int ti = blockIdx.x, tj = blockIdx.y;      // k-tile, n-tile
  int c = threadIdx.x & 31, r0 = threadIdx.x >> 5;
#pragma unroll
  for (int rr = 0; rr < 4; ++rr) {
    int r = r0 + rr * 8;
    tile[r][c] = W[(ti * 32 + r) * DM + tj * 32 + c];
  }
  __syncthreads();
  unsigned short* Out = (z == 0) ? Wqt : (z == 1) ? Wkt : (z == 2) ? Wvt : Wot;
#pragma unroll
  for (int rr = 0; rr < 4; ++rr) {
    int a = r0 + rr * 8;                     // n within tile
    float v = tile[c][a];                    // = W[ti*32+c][tj*32+a]
    Out[(tj * 32 + a) * DM + ti * 32 + c] = f2bf(v);
  }
}

// ---------------- k2: QKV projection GEMM (dbuf, counted vmcnt) -----------
__global__ __launch_bounds__(256) void k_gemm_qkv(
    const unsigned short* __restrict__ xb,
    const unsigned short* __restrict__ Wqt, const unsigned short* __restrict__ Wkt,
    const unsigned short* __restrict__ Wvt,
    const float* __restrict__ bq, const float* __restrict__ bk,
    const float* __restrict__ bv,
    unsigned short* __restrict__ Q, unsigned short* __restrict__ Ko,
    unsigned short* __restrict__ Vt) {
  __shared__ __align__(16) unsigned short Al[2][128 * 64];
  __shared__ __align__(16) unsigned short Bl[2][128 * 64];
  int z = blockIdx.z;
  const unsigned short* Wt = (z == 0) ? Wqt : (z == 1) ? Wkt : Wvt;
  const float* bias = (z == 0) ? bq : (z == 1) ? bk : bv;

  int m0 = blockIdx.x * 128, n0 = blockIdx.y * 128;
  int tid = threadIdx.x, lane = tid & 63, wave = tid >> 6;
  int wr = wave >> 1, wc = wave & 1;
  int l15 = lane & 15, lg = lane >> 4;
  int r3 = lane >> 3, s3 = lane & 7;
  int gsw = (s3 ^ r3) << 4;      // pre-swizzled source slot (bytes), row&7 == r3
  int swz = l15 & 7;             // read-side row XOR

  f32x4 acc[4][4] = {};

  auto stage = [&](int kb, int b) {
#pragma unroll
    for (int c = 0; c < 4; ++c) {
      int rb = c * 32 + wave * 8;            // wave-uniform row base (mult of 8)
      gload_lds16((const char*)xb + (size_t)(m0 + rb + r3) * 2048 + kb * 128 + gsw,
                  (char*)&Al[b][0] + rb * 128);
      gload_lds16((const char*)Wt + (size_t)(n0 + rb + r3) * 2048 + kb * 128 + gsw,
                  (char*)&Bl[b][0] + rb * 128);
    }
  };

  stage(0, 0);
  stage(1, 1);

  for (int kb = 0; kb < 16; ++kb) {
    if (kb < 15) asm volatile("s_waitcnt vmcnt(8)" ::: "memory");
    else         asm volatile("s_waitcnt vmcnt(0)" ::: "memory");
    barrier_raw();
    int b = kb & 1;
#pragma unroll
    for (int ks = 0; ks < 2; ++ks) {
      int slot = lg + 4 * ks;
      int sofs = ((slot ^ swz) << 4);
      bf16x8 a[4], bfr[4];
#pragma unroll
      for (int mt = 0; mt < 4; ++mt)
        a[mt] = *(const bf16x8*)((const char*)&Al[b][0] + (wr * 64 + mt * 16 + l15) * 128 + sofs);
#pragma unroll
      for (int nt = 0; nt < 4; ++nt)
        bfr[nt] = *(const bf16x8*)((const char*)&Bl[b][0] + (wc * 64 + nt * 16 + l15) * 128 + sofs);
#pragma unroll
      for (int mt = 0; mt < 4; ++mt)
#pragma unroll
        for (int nt = 0; nt < 4; ++nt)
          acc[mt][nt] = mfma16(a[mt], bfr[nt], acc[mt][nt]);
    }
    barrier_raw();
    if (kb < 14) stage(kb + 2, b);
  }

#pragma unroll
  for (int nt = 0; nt < 4; ++nt) {
    int n = n0 + wc * 64 + nt * 16 + l15;
    float bb = bias[n];
    int h = n >> 6, dk = n & 63;
#pragma unroll
    for (int mt = 0; mt < 4; ++mt) {
      int mbase = m0 + wr * 64 + mt * 16 + lg * 4;
      int bidx = mbase >> 11, s = mbase & 2047;
      if (z < 2) {
        unsigned short* Out = (z == 0) ? Q : Ko;
#pragma unroll
        for (int r = 0; r < 4; ++r)
          Out[(((size_t)(bidx * NH + h)) * SEQ + s + r) * DKH + dk] =
              f2bf(acc[mt][nt][r] + bb);
      } else {
        ushort4 pk;
        pk.x = f2bf(acc[mt][nt][0] + bb);
        pk.y = f2bf(acc[mt][nt][1] + bb);
        pk.z = f2bf(acc[mt][nt][2] + bb);
        pk.w = f2bf(acc[mt][nt][3] + bb);
        *(ushort4*)&Vt[((size_t)(bidx * NH + h) * DKH + dk) * SEQ + s] = pk;
      }
    }
  }
}

// ---------------- k3: chunk-causal flash attention (v10) ------------------
// v9 + (i) single-barrier T3-min loop: stage(j+1) issued BEFORE compute(j),
// vmcnt(0)+one barrier at tile end (stage latency hides under compute);
// (ii) lsum via ones-MFMA into acc_l (kills 15 VALU adds/tile + epilogue
// shuffles). In-register PV bijection, fixed-max softmax unchanged.
__global__ __launch_bounds__(256) void k_attn(
    const unsigned short* __restrict__ Qg, const unsigned short* __restrict__ Kg,
    const unsigned short* __restrict__ Vtg, const float* __restrict__ rel_bias,
    unsigned short* __restrict__ AOh) {
  __shared__ __align__(16) unsigned short Kl[2][64 * 64];
  __shared__ __align__(16) unsigned short Vl[2][64 * 64];
  __shared__ float biasl[257];

  int blk = blockIdx.x;
  int bh = blk & 31;
  int g = blk >> 5;
  int qc = (g < 16) ? (31 - g) : (g - 16);   // balanced per-CU quads
  int h = bh & 15, bidx = bh >> 4;
  int tid = threadIdx.x, lane = tid & 63, wave = tid >> 6;
  int l15 = lane & 15, lg = lane >> 4;
  int r3 = lane >> 3, s3 = lane & 7;
  int gsw = (s3 ^ r3) * 16;   // pre-swizzled source slot (bytes)

  const float C1L = 0.125f * LOG2E;

  // bias table pre-scaled: (rel_bias - 6) * log2(e)
  for (int i = tid; i < 257; i += 256)
    biasl[i] = rel_bias[i * NH + h] * LOG2E - 6.0f * LOG2E;

  // Q fragments in registers for the whole block (B-operand: lane l15 = q)
  int qrow = qc * 64 + wave * 16 + l15;
  const unsigned short* qptr = Qg + ((size_t)bh * SEQ + qrow) * DKH + lg * 8;
  bf16x8 qf0 = *(const bf16x8*)(qptr);
  bf16x8 qf1 = *(const bf16x8*)(qptr + 32);

  const char* kcb = (const char*)(Kg + (size_t)bh * SEQ * DKH);
  const char* vcb = (const char*)(Vtg + (size_t)bh * DKH * SEQ);

  // stage K/V chunk j into buffer b: LDS[row][slot16] = G[row][slot16 ^ (row&7)]
  auto stage = [&](int j, int b) {
    const char* kj = kcb + (size_t)j * (64 * DKH * 2);
    const char* vj = vcb + (size_t)j * 128;
#pragma unroll
    for (int c = 0; c < 2; ++c) {
      int rb = wave * 16 + c * 8;          // wave-uniform row base
      gload_lds16(kj + (size_t)(rb + r3) * 128 + gsw,
                  (char*)&Kl[b][0] + rb * 128);
      gload_lds16(vj + (size_t)(rb + r3) * (SEQ * 2) + gsw,
                  (char*)&Vl[b][0] + rb * 128);
    }
  };

  f32x4 acc[4] = {};
  f32x4 accl = {};                       // lsum via ones-MFMA
  bf16x8 ones;
#pragma unroll
  for (int jj = 0; jj < 8; ++jj) ones[jj] = (__bf16)1.0f;

  float cfar = rel_bias[256 * NH + h] * LOG2E - 6.0f * LOG2E;
  int swz = (l15 & 7);

  // V-read byte offsets within a row for the 4 kt chunks (8B each)
  int vo[4];
#pragma unroll
  for (int kt = 0; kt < 4; ++kt)
    vo[kt] = (((kt * 2 + (lg >> 1)) ^ swz) << 4) + ((lg & 1) << 3);

  // prologue: tile 0 staged + biasl visible
  stage(0, 0);
  asm volatile("s_waitcnt vmcnt(0)" ::: "memory");
  barrier_raw();

  for (int j = 0; j <= qc; ++j) {
    int cur = j & 1;
    if (j < qc) stage(j + 1, cur ^ 1);   // issue next-tile loads FIRST

    const char* Kc = (const char*)&Kl[cur][0];
    const char* Vc = (const char*)&Vl[cur][0];

    // QK^T swapped: A = K rows (m = key), B = Q (n = q = l15)
    // sa[kt][r] -> k = j*64 + kt*16 + lg*4 + r ; q = qrow (lane-fixed)
    f32x4 sa[4] = {};
    __builtin_amdgcn_s_setprio(1);
#pragma unroll
    for (int ks = 0; ks < 2; ++ks) {
      bf16x8 qa = ks ? qf1 : qf0;
      int slot = lg + 4 * ks;
#pragma unroll
      for (int kt = 0; kt < 4; ++kt) {
        bf16x8 kfr = *(const bf16x8*)(Kc + (kt * 16 + l15) * 128 + ((slot ^ swz) * 16));
        sa[kt] = mfma16(kfr, qa, sa[kt]);
      }
    }
    __builtin_amdgcn_s_setprio(0);

    // p = exp2(s*C1L + bias); far tiles (j <= qc-3) have constant bias
    float p[4][4];
    if (j >= qc - 2) {
      int kb0 = j * 64 + lg * 4;
#pragma unroll
      for (int kt = 0; kt < 4; ++kt)
#pragma unroll
        for (int r = 0; r < 4; ++r) {
          int rel = qrow - (kb0 + kt * 16 + r);
          rel = min(max(rel, -128), 128) + 128;
          p[kt][r] = EXP2(fmaf(sa[kt][r], C1L, biasl[rel]));
        }
    } else {
#pragma unroll
      for (int kt = 0; kt < 4; ++kt)
#pragma unroll
        for (int r = 0; r < 4; ++r)
          p[kt][r] = EXP2(fmaf(sa[kt][r], C1L, cfar));
    }

    // pack P in-register as PV A-fragments (lane l15 = q = A's m-row):
    // pfr_h slot jj holds key (2h + (jj>>2))*16 + lg*4 + (jj&3) — lane-local.
    bf16x8 pfr0, pfr1;
#pragma unroll
    for (int jj = 0; jj < 4; ++jj) {
      pfr0[jj]     = (__bf16)p[0][jj];
      pfr0[jj + 4] = (__bf16)p[1][jj];
      pfr1[jj]     = (__bf16)p[2][jj];
      pfr1[jj + 4] = (__bf16)p[3][jj];
    }

    // PV: B = V assembled with the SAME key bijection (2x b64 per dt,half)
    __builtin_amdgcn_s_setprio(1);
#pragma unroll
    for (int dt = 0; dt < 4; ++dt) {
      const char* vrow = Vc + (dt * 16 + l15) * 128;
      uint2 t0 = *(const uint2*)(vrow + vo[0]);
      uint2 t1 = *(const uint2*)(vrow + vo[1]);
      uint2 t2 = *(const uint2*)(vrow + vo[2]);
      uint2 t3 = *(const uint2*)(vrow + vo[3]);
      uint4 w0, w1;
      w0.x = t0.x; w0.y = t0.y; w0.z = t1.x; w0.w = t1.y;
      w1.x = t2.x; w1.y = t2.y; w1.z = t3.x; w1.w = t3.y;
      acc[dt] = mfma16(pfr0, *(const bf16x8*)&w0, acc[dt]);
      acc[dt] = mfma16(pfr1, *(const bf16x8*)&w1, acc[dt]);
    }
    // lsum: C[q][*] = sum_k P — replaces 15 VALU adds with 2 MFMAs
    accl = mfma16(pfr0, ones, accl);
    accl = mfma16(pfr1, ones, accl);
    __builtin_amdgcn_s_setprio(0);

    if (j < qc) {
      asm volatile("s_waitcnt vmcnt(0)" ::: "memory");  // next tile landed
      barrier_raw();                                    // all done reading cur
    }
  }

  // epilogue: normalize (accl[r] = lsum for q-row lg*4+r, no shuffles)
#pragma unroll
  for (int r = 0; r < 4; ++r) {
    float inv = 1.0f / accl[r];
    int s = qc * 64 + wave * 16 + lg * 4 + r;
    size_t row = (size_t)bidx * SEQ + s;
#pragma unroll
    for (int dt = 0; dt < 4; ++dt) {
      float v = acc[dt][r] * inv;
      int col = h * 64 + dt * 16 + l15;
      AOh[row * DM + col] = f2bf(v);
    }
  }
}

// ---------------- k4: output GEMM, 64x128 tile (dbuf, vmcnt(6)) -----------
__global__ __launch_bounds__(256) void k_gemm_out(
    const unsigned short* __restrict__ Ab, const unsigned short* __restrict__ Bt,
    const float* __restrict__ bo, float* __restrict__ out) {
  __shared__ __align__(16) unsigned short Al[2][64 * 64];
  __shared__ __align__(16) unsigned short Bl[2][128 * 64];

  int m0 = blockIdx.x * 64, n0 = blockIdx.y * 128;
  int tid = threadIdx.x, lane = tid & 63, wave = tid >> 6;
  int wr = wave >> 1, wc = wave & 1;
  int l15 = lane & 15, lg = lane >> 4;
  int r3 = lane >> 3, s3 = lane & 7;
  int gsw = (s3 ^ r3) << 4;
  int swz = l15 & 7;

  f32x4 acc[2][4] = {};

  auto stage = [&](int kb, int b) {
#pragma unroll
    for (int c = 0; c < 2; ++c) {       // A: 64 rows
      int rb = c * 32 + wave * 8;
      gload_lds16((const char*)Ab + (size_t)(m0 + rb + r3) * 2048 + kb * 128 + gsw,
                  (char*)&Al[b][0] + rb * 128);
    }
#pragma unroll
    for (int c = 0; c < 4; ++c) {       // B: 128 rows
      int rb = c * 32 + wave * 8;
      gload_lds16((const char*)Bt + (size_t)(n0 + rb + r3) * 2048 + kb * 128 + gsw,
                  (char*)&Bl[b][0] + rb * 128);
    }
  };

  stage(0, 0);
  stage(1, 1);

  for (int kb = 0; kb < 16; ++kb) {
    if (kb < 15) asm volatile("s_waitcnt vmcnt(6)" ::: "memory");
    else         asm volatile("s_waitcnt vmcnt(0)" ::: "memory");
    barrier_raw();
    int b = kb & 1;
#pragma unroll
    for (int ks = 0; ks < 2; ++ks) {
      int slot = lg + 4 * ks;
      int sofs = ((slot ^ swz) << 4);
      bf16x8 a[2], bfr[4];
#pragma unroll
      for (int mt = 0; mt < 2; ++mt)
        a[mt] = *(const bf16x8*)((const char*)&Al[b][0] + (wr * 32 + mt * 16 + l15) * 128 + sofs);
#pragma unroll
      for (int nt = 0; nt < 4; ++nt)
        bfr[nt] = *(const bf16x8*)((const char*)&Bl[b][0] + (wc * 64 + nt * 16 + l15) * 128 + sofs);
#pragma unroll
      for (int mt = 0; mt < 2; ++mt)
#pragma unroll
        for (int nt = 0; nt < 4; ++nt)
          acc[mt][nt] = mfma16(a[mt], bfr[nt], acc[mt][nt]);
    }
    barrier_raw();
    if (kb < 14) stage(kb + 2, b);
  }

#pragma unroll
  for (int nt = 0; nt < 4; ++nt) {
    int n = n0 + wc * 64 + nt * 16 + l15;
    float bb = bo[n];
#pragma unroll
    for (int mt = 0; mt < 2; ++mt) {
      int mbase = m0 + wr * 32 + mt * 16 + lg * 4;
#pragma unroll
      for (int r = 0; r < 4; ++r)
        out[(size_t)(mbase + r) * DM + n] = acc[mt][nt][r] + bb;
    }
  }
}

// ---------------- launch ---------------------------------------------------
extern "C" void kernel_launch(void* const* d_in, const int* in_sizes, int n_in,
                              void* d_out, int out_size, void* d_ws, size_t ws_size,
                              hipStream_t stream) {
  const float* x  = (const float*)d_in[0];
  const float* Wq = (const float*)d_in[1];
  const float* bq = (const float*)d_in[2];
  const float* Wk = (const float*)d_in[3];
  const float* bk = (const float*)d_in[4];
  const float* Wv = (const float*)d_in[5];
  const float* bv = (const float*)d_in[6];
  const float* Wo = (const float*)d_in[7];
  const float* bo = (const float*)d_in[8];
  const float* rb = (const float*)d_in[9];
  float* out = (float*)d_out;

  char* ws = (char*)d_ws;
  size_t off = 0;
  auto alloc = [&](size_t bytes) {
    char* p = ws + off; off += (bytes + 255) & ~(size_t)255; return p;
  };
  unsigned short* xb   = (unsigned short*)alloc((size_t)NROW * DM * 2);
  unsigned short* Wqt  = (unsigned short*)alloc((size_t)DM * DM * 2);
  unsigned short* Wkt  = (unsigned short*)alloc((size_t)DM * DM * 2);
  unsigned short* Wvt  = (unsigned short*)alloc((size_t)DM * DM * 2);
  unsigned short* Wot  = (unsigned short*)alloc((size_t)DM * DM * 2);
  unsigned short* Qb   = (unsigned short*)alloc((size_t)NROW * DM * 2);
  unsigned short* Kb   = (unsigned short*)alloc((size_t)NROW * DM * 2);
  unsigned short* Vtb  = (unsigned short*)alloc((size_t)NROW * DM * 2);
  unsigned short* AOh  = (unsigned short*)alloc((size_t)NROW * DM * 2);

  k_cvt_x<<<dim3(NROW * DM / 4 / 256), dim3(256), 0, stream>>>(x, xb);
  k_cvt_w<<<dim3(32, 32, 4), dim3(256), 0, stream>>>(Wq, Wk, Wv, Wo,
                                                     Wqt, Wkt, Wvt, Wot);
  k_gemm_qkv<<<dim3(32, 8, 3), dim3(256), 0, stream>>>(xb, Wqt, Wkt, Wvt,
                                                       bq, bk, bv, Qb, Kb, Vtb);
  k_attn<<<dim3(1024), dim3(256), 0, stream>>>(Qb, Kb, Vtb, rb, AOh);
  k_gemm_out<<<dim3(64, 8), dim3(256), 0, stream>>>(AOh, Wot, bo, out);
}